// Round 14
// baseline (689.399 us; speedup 1.0000x reference)
//
#include <hip/hip_runtime.h>
#include <math.h>

#define BB 512
#define NN 16
#define CC 256
#define KK 8192
#define BNC (BB*NN*CC)

typedef unsigned short u16;
typedef __attribute__((ext_vector_type(8))) short bf16x8;
typedef __attribute__((ext_vector_type(4))) float f32x4;

__device__ __forceinline__ u16 f2bf(float x) {
    unsigned u = __float_as_uint(x);
    unsigned r = (u + 0x7fffu + ((u >> 16) & 1u)) >> 16;
    return (u16)r;
}

__device__ __forceinline__ void gl2lds16(const void* g, void* l) {
    __builtin_amdgcn_global_load_lds(
        (const __attribute__((address_space(1))) void*)g,
        (__attribute__((address_space(3))) void*)l,
        16, 0, 0);
}

__device__ __forceinline__ void gl2lds4(const void* g, void* l) {
    __builtin_amdgcn_global_load_lds(
        (const __attribute__((address_space(1))) void*)g,
        (__attribute__((address_space(3))) void*)l,
        4, 0, 0);
}

// ---------------------------------------------------------------------------
// merged: stores negated-bf16 emb AND 0.5*|e|^2 from one pass over emb.
__global__ void esq_cvt_kernel(const float* __restrict__ emb,
                               float* __restrict__ e_sq,
                               u16* __restrict__ out) {
    int gid = blockIdx.x * blockDim.x + threadIdx.x;
    int lane = gid & 63;
    float4 v = ((const float4*)emb)[gid];
    ushort4 o;
    o.x = f2bf(-v.x); o.y = f2bf(-v.y); o.z = f2bf(-v.z); o.w = f2bf(-v.w);
    ((ushort4*)out)[gid] = o;
    float s = v.x*v.x + v.y*v.y + v.z*v.z + v.w*v.w;
    #pragma unroll
    for (int m = 32; m >= 1; m >>= 1) s += __shfl_xor(s, m, 64);
    if (lane == 0) e_sq[gid >> 6] = 0.5f * s;
}

// initial pool for pn=1
__global__ void init_pool_kernel(const float* __restrict__ f,
                                 u16* __restrict__ rest_bf) {
    int b = blockIdx.x;
    int c = threadIdx.x;
    const float* base = f + (size_t)b * NN * CC + c;
    float acc = 0.f;
    #pragma unroll
    for (int n = 0; n < NN; ++n) acc += base[(size_t)n * CC];
    rest_bf[(size_t)b * CC + c] = f2bf(acc * (1.0f / 16.0f));
}

// ---------------------------------------------------------------------------
__device__ __forceinline__ unsigned long long shfl_xor_u64(unsigned long long v, int m) {
    unsigned lo = (unsigned)v, hi = (unsigned)(v >> 32);
    lo = __shfl_xor(lo, m, 64);
    hi = __shfl_xor(hi, m, 64);
    return ((unsigned long long)hi << 32) | lo;
}

// MFMA distance+argmin, v15 (continuous stream, 16-deep ring, counted vmcnt):
//  v14 floors: LDS-read 20.5us (binding, j=2) vs MFMA 16.6; measured ~42 =
//  50% of binding pipe. The drain-per-cb (vmcnt(0)) is the residual stall;
//  T4 (m218): counted-never-drained = +38-73% within phase-split loops.
//  - One continuous chunk stream (chunk = 64 codes x 64B = 4KB) across the
//    whole cpb; NO cb-level drain anywhere.
//  - Ring = 16 chunks (64KB = the proven no-spill LDS regime, 2 blocks/CU,
//    16 waves/CU with the j=2 register diet: ~100 regs).
//  - Phase = pair of chunks: {stage pair p+6 (1 gl2lds16/thread: waves 0-3
//    chunk 2p+12, waves 4-7 chunk 2p+13) -> vmcnt(6) -> barrier -> 8
//    ds_read_b128 -> 16 MFMA}. 6 pairs (12 chunks, ~1500+ cyc of flight)
//    stay outstanding across every barrier.
//  - Write-slot hazard: stage targets slot (2p+12)&15 = chunk 2p-4's slot,
//    read 2 phases (2 barriers) ago; max wave skew < 1 barrier interval ->
//    no lgkm drain needed (compiler's lgkm waits before MFMA suffice).
//  - Prologue: esq strip first (retires inside phase 0's vmcnt(6)), then
//    pairs 0..5. Tail: source-clamped, dest-slot unclamped (count exact).
//  - gx granule swizzle via pre-swizzled global source: 0 bank conflicts
//    (proven v6-v14). No setprio (lockstep), no sched_barrier (m141).
__global__ __launch_bounds__(512, 2) void dist_mfma_kernel(
        const u16* __restrict__ A, const u16* __restrict__ Bm,
        const float* __restrict__ e_sq,
        unsigned long long* __restrict__ packed, int cpb) {
    __shared__ __align__(16) u16 sC[32768];   // 64KB ring: 16 chunks x 4KB
    __shared__ __align__(16) float sE[512];   // whole esq strip (cpb <= 512)
    const int tid = threadIdx.x;
    const int w = tid >> 6, l = tid & 63;     // 8 waves
    const int r0 = blockIdx.x * 256;
    const int c0 = blockIdx.y * cpb;
    const int nch = cpb >> 3;    // 4KB chunks in this block's code range
    const int ncb2 = cpb >> 6;   // 64-code groups (4 phases each)
    const int arow = l & 15;
    const int aq   = l >> 4;

    // ---- resident row fragments: wave owns rows r0+w*32 .. +31 ----
    bf16x8 bf[2][8];
    {
        const u16* fb = A + (((size_t)(r0 + w * 32 + arow)) << 8) + aq * 8;
        #pragma unroll
        for (int j = 0; j < 2; ++j)
            #pragma unroll
            for (int kc = 0; kc < 8; ++kc)
                bf[j][kc] = *(const bf16x8*)(fb + (j << 12) + (kc << 5));
    }

    // ---- esq strip (issued BEFORE chunk stages: retires at phase 0's wait)
    for (int n = tid; n < cpb; n += 512)
        gl2lds4(e_sq + c0 + n, (char*)sE + (size_t)(n - l) * 4);

    // ---- staging map: thread covers 16B slot (tid&255) of its pair-chunk.
    // code crel = (tid&255)>>2; stored granule (tid&3) receives actual
    // granule g = (tid&3)^((tid>>3)&3) (pre-swizzled source, linear dest).
    const int crel = (tid & 255) >> 2;
    const int g = (tid & 3) ^ ((tid >> 3) & 3);
    const u16* Pb = Bm + (((size_t)(c0 + crel)) << 8) + g * 8;

    // stage pair pp_: chunk tc = 2*pp_ + (tid>>8); dest slot tc&15 (unclamped),
    // source clamped to nch-1 (tail re-stages last chunk harmlessly).
    #define STAGE_PAIR(pp_) { \
        int tc_ = ((pp_) << 1) + (tid >> 8); \
        const int td_ = tc_ & 15; \
        if (tc_ >= nch) tc_ = nch - 1; \
        const u16* s_ = Pb + (((size_t)(tc_ >> 3)) << 14) + ((tc_ & 7) << 5); \
        gl2lds16(s_, (char*)sC + (td_ << 12) + ((w & 3) << 10)); }

    STAGE_PAIR(0) STAGE_PAIR(1) STAGE_PAIR(2)
    STAGE_PAIR(3) STAGE_PAIR(4) STAGE_PAIR(5)

    const int gx = aq ^ ((arow >> 1) & 3);   // read-side granule swizzle
    float bestd[2];
    int   bestk[2];
    #pragma unroll
    for (int j = 0; j < 2; ++j) { bestd[j] = 1e30f; bestk[j] = 0; }

    f32x4 acc[4][2];
    for (int cb = 0; cb < ncb2; ++cb) {
        #pragma unroll
        for (int ph = 0; ph < 4; ++ph) {
            const int t = cb * 8 + ph * 2;       // first chunk of this phase
            STAGE_PAIR((t >> 1) + 6)
            // my pair-t loads landed; 6 newer pairs stay in flight
            asm volatile("s_waitcnt vmcnt(6)" ::: "memory");
            __builtin_amdgcn_s_barrier();        // all waves' pair-t landed
            if (ph == 0) {
                #pragma unroll
                for (int i = 0; i < 4; ++i) {
                    f32x4 ev = *(const f32x4*)(sE + cb * 64 + i * 16 + (aq << 2));
                    #pragma unroll
                    for (int j = 0; j < 2; ++j) acc[i][j] = ev;
                }
            }
            #pragma unroll
            for (int h = 0; h < 2; ++h) {
                const int kc = ph * 2 + h;
                const u16* cbp = sC + (((t + h) & 15) << 11);
                bf16x8 cf[4];
                #pragma unroll
                for (int i = 0; i < 4; ++i)
                    cf[i] = *(const bf16x8*)(cbp + ((i * 16 + arow) << 5) + (gx << 3));
                #pragma unroll
                for (int i = 0; i < 4; ++i)
                    #pragma unroll
                    for (int j = 0; j < 2; ++j)
                        acc[i][j] = __builtin_amdgcn_mfma_f32_16x16x32_bf16(
                                        cf[i], bf[j][kc], acc[i][j], 0, 0, 0);
            }
        }

        // fold: acc holds 0.5*d for this 64-code group (register-only)
        #pragma unroll
        for (int i = 0; i < 4; ++i)
            #pragma unroll
            for (int r = 0; r < 4; ++r) {
                const int k = c0 + cb * 64 + i * 16 + (aq << 2) + r;
                #pragma unroll
                for (int j = 0; j < 2; ++j) {
                    const float d = acc[i][j][r];
                    if (d < bestd[j]) { bestd[j] = d; bestk[j] = k; }
                }
            }
    }
    #undef STAGE_PAIR

    // merge across the 4 aq-lanes holding the same f-row, then global merge
    #pragma unroll
    for (int j = 0; j < 2; ++j) {
        unsigned u = __float_as_uint(bestd[j]);
        u = (u & 0x80000000u) ? ~u : (u | 0x80000000u);
        unsigned long long p = ((unsigned long long)u << 32) | (unsigned)bestk[j];
        unsigned long long o = shfl_xor_u64(p, 16);
        if (o < p) p = o;
        o = shfl_xor_u64(p, 32);
        if (o < p) p = o;
        if (aq == 0)
            atomicMin(&packed[r0 + w * 32 + j * 16 + arow], p);
    }
}

// ---------------------------------------------------------------------------
// Fused update: f_hat eliminated via f_hat == f - f_rest (v13).
__global__ void update_pool_kernel(const float* __restrict__ f,
                                   const float* __restrict__ emb,
                                   const unsigned long long* __restrict__ packed,
                                   float* __restrict__ f_rest,
                                   float* __restrict__ out,
                                   float* __restrict__ slots,
                                   u16* __restrict__ rest_bf, int pn) {
    int b = blockIdx.x;
    int c = threadIdx.x;
    __shared__ int sk[NN];
    __shared__ float red[4];
    if (threadIdx.x < pn)
        sk[threadIdx.x] = (int)(unsigned)(packed[b * pn + threadIdx.x] & 0xffffffffull);
    __syncthreads();

    float fr[NN];
    float acc_sq = 0.f;
    #pragma unroll
    for (int n = 0; n < NN; ++n) {
        double pos = (n + 0.5) * ((double)pn / 16.0) - 0.5;
        if (pos < 0.0) pos = 0.0;
        int i0 = (int)floor(pos);
        if (i0 > pn - 1) i0 = pn - 1;
        int i1 = i0 + 1;
        if (i1 > pn - 1) i1 = pn - 1;
        double frac = pos - (double)i0;
        float w1 = (float)frac;
        float w0 = (float)(1.0 - frac);
        float h = w0 * emb[(size_t)sk[i0] * CC + c] + w1 * emb[(size_t)sk[i1] * CC + c];
        size_t off = ((size_t)b * NN + n) * CC + c;
        float fre = f_rest[off] - h;
        fr[n] = fre;
        acc_sq += fre * fre;
        if (pn < NN) {
            f_rest[off] = fre;
        } else {
            out[off] = f[off] - fre;   // f_hat = f - f_rest
        }
    }

    int wv = threadIdx.x >> 6, ln = threadIdx.x & 63;
    #pragma unroll
    for (int m = 32; m >= 1; m >>= 1) acc_sq += __shfl_xor(acc_sq, m, 64);
    if (ln == 0) red[wv] = acc_sq;

    int pn2 = pn + 1;
    if (pn < NN) {
        for (int p = 0; p < pn2; ++p) {
            int s = (p * NN) / pn2;
            int e = ((p + 1) * NN + pn2 - 1) / pn2;
            float v = 0.f;
            for (int n = s; n < e; ++n) v += fr[n];
            v *= 1.0f / (float)(e - s);
            rest_bf[((size_t)(b * pn2 + p)) * CC + c] = f2bf(v);
        }
    }
    __syncthreads();
    if (threadIdx.x == 0)
        atomicAdd(&slots[b & 255], (red[0] + red[1]) + (red[2] + red[3]));
}

// ---------------------------------------------------------------------------
__global__ void final_kernel(const float* __restrict__ slots, float* __restrict__ out_scalars) {
    float v = slots[threadIdx.x];
    #pragma unroll
    for (int m = 32; m >= 1; m >>= 1) v += __shfl_xor(v, m, 64);
    __shared__ float red[4];
    int wv = threadIdx.x >> 6, ln = threadIdx.x & 63;
    if (ln == 0) red[wv] = v;
    __syncthreads();
    if (threadIdx.x == 0) {
        float S = (red[0] + red[1]) + (red[2] + red[3]);
        float qlat = S / (float)BNC / (float)NN;
        out_scalars[0] = 0.25f * qlat;   // commit
        out_scalars[1] = qlat;           // qlat
    }
}

// ---------------------------------------------------------------------------
extern "C" void kernel_launch(void* const* d_in, const int* in_sizes, int n_in,
                              void* d_out, int out_size, void* d_ws, size_t ws_size,
                              hipStream_t stream) {
    (void)in_sizes; (void)n_in; (void)out_size; (void)ws_size;
    const float* f   = (const float*)d_in[0];   // [B, N, C]
    const float* emb = (const float*)d_in[1];   // [K, C]
    float* out = (float*)d_out;                 // f_hat [B*N*C] + 2 scalars

    float* ws      = (float*)d_ws;
    float* f_rest  = ws;                                   // BNC floats
    float* r2_pad  = f_rest + BNC;                         // 8192 (unused, layout keep)
    float* e_sq    = r2_pad + BB * NN;                     // K (0.5*|e|^2)
    float* slots   = e_sq + KK;                            // 256
    unsigned long long* packed_all = (unsigned long long*)(slots + 256);  // 512*136
    u16* rest_bf = (u16*)(packed_all + (size_t)BB * 136);  // 8192*256 bf16
    u16* emb_bf  = rest_bf + (size_t)BB * NN * CC;         // K*C bf16 (negated)

    hipMemcpyAsync(f_rest, f, (size_t)BNC * sizeof(float), hipMemcpyDeviceToDevice, stream);
    hipMemsetAsync(slots, 0, 256 * sizeof(float), stream);
    hipMemsetAsync(packed_all, 0xFF, (size_t)BB * 136 * sizeof(unsigned long long), stream);
    esq_cvt_kernel<<<KK * CC / 4 / 256, 256, 0, stream>>>(emb, e_sq, emb_bf);
    init_pool_kernel<<<BB, 256, 0, stream>>>(f, rest_bf);

    // splits: target >= 512 blocks where cpb >= 64 allows; cpb = 8192/splits
    static const int splits_tab[17] =
        {0,128,128,128,64,64,64,64,32,32,32,32,32,32,32,32,16};

    for (int pn = 1; pn <= NN; ++pn) {
        unsigned long long* packed = packed_all + (size_t)BB * (pn * (pn - 1) / 2);
        int splits = splits_tab[pn];
        int cpb = KK / splits;
        dim3 grid(BB * pn / 256, splits);
        dist_mfma_kernel<<<grid, 512, 0, stream>>>(rest_bf, emb_bf, e_sq, packed, cpb);
        update_pool_kernel<<<BB, 256, 0, stream>>>(f, emb, packed, f_rest, out,
                                                   slots, rest_bf, pn);
    }
    final_kernel<<<1, 256, 0, stream>>>(slots, out + BNC);
}